// Round 7
// baseline (147.997 us; speedup 1.0000x reference)
//
#include <hip/hip_runtime.h>

// StateSpaceDiffusionModel — MFMA formulation, round 9: SPMD group-scan.
//
//   r_m = A·p_m + S·u_m,  p_{m+1} = r_m,  y_m = G1·p_m + G2·r_m,  A = S·W.
// Constant transition A => parallel prefix over 4 groups of 8 chunks:
//   C_g  = zero-init local final state of group g       (pass 1, parallel)
//   P_g  = sum_{g'<g} (A^8)^{g-g'-1} C_{g'}             (tiny scan, A^8 Horner)
//   pass2: replay group g from true P_g, emitting y     (parallel)
// Lessons baked in from rounds 3-6: NO wid-divergent main loops (allocator
// spills divergent-role loop state: R4/R5/R6 kept 80/104/64 VGPR), NO
// per-step cross-wave barriers (skew). All 4 waves run IDENTICAL pass1/pass2
// code on their own chunks + own LDS slab (R2's proven structure), barriers
// only around the 2-matvec scan. A-frags in registers (serial critical path);
// S/G1/G2 as pre-converted bf16 LDS tables (saves 64 loop-live VGPR).
// u re-read in pass 2 (67 MB total, L3-resident). A^8 via 3 prologue MFMA
// squarings (4-term hi/lo). 2 blocks/CU (LDS 69.6KB), 8 waves/CU, 2/SIMD.
//
// mfma_f32_16x16x32_bf16 layouts (m89/m120):
//   A[m][k]: m=lane&15, k=(lane>>4)*8+j (+32*tk)
//   B[k][n]: k=(lane>>4)*8+j (+32*tk), n=lane&15
//   C[m][n]: n=lane&15, m=(lane>>4)*4+reg
//
// LDS pool (69632 B), phase-aliased:
//   [    0, 1536) taps f32[3][128]      (0=S, 1=G2, 2=G1 pads)
//   [ 1536, 2048) wPad f32[128]
//   [ 2048,19456) stA f32[64][68]       (A, then A^4; pass1+: 4x per-wave scratch [16][68])
//   [19456,36864) stB f32[64][68]       (A^2, then A^8; post-scan: g2T table)
//   [36864,53248) sT  bf16x8[4][2][2][64]
//   [53248,69632) g1T bf16x8[4][2][2][64]

namespace {

constexpr int kH = 512;
constexpr int kL = 2048;

typedef __attribute__((ext_vector_type(8))) short bf16x8;
typedef __attribute__((ext_vector_type(4))) float f32x4;

#define MFMA(A, B, C) __builtin_amdgcn_mfma_f32_16x16x32_bf16((A), (B), (C), 0, 0, 0)

__device__ inline unsigned int cvt_pk_bf16(float lo, float hi) {
  unsigned int r;
  asm("v_cvt_pk_bf16_f32 %0, %1, %2" : "=v"(r) : "v"(lo), "v"(hi));
  return r;
}

union B8U4 { bf16x8 v; unsigned int u[4]; };

__device__ inline void cvt_split8(const f32x4 a, const f32x4 b, bf16x8& fh, bf16x8& fl) {
  B8U4 H, L;
  float x[8];
  #pragma unroll
  for (int j = 0; j < 4; ++j) { x[j] = a[j]; x[4 + j] = b[j]; }
  #pragma unroll
  for (int d = 0; d < 4; ++d) {
    const float x0 = x[2 * d], x1 = x[2 * d + 1];
    const unsigned int hp = cvt_pk_bf16(x0, x1);
    const float h0 = __uint_as_float(hp << 16);
    const float h1 = __uint_as_float(hp & 0xFFFF0000u);
    H.u[d] = hp;
    L.u[d] = cvt_pk_bf16(x0 - h0, x1 - h1);
  }
  fh = H.v; fl = L.v;
}

// Toeplitz A-operand fragment from a 128-tap array: value = tp[n0 - j]
__device__ inline void gen_frag(const float* tp, int n0, bf16x8& fh, bf16x8& fl) {
  float t[8];
  #pragma unroll
  for (int j = 0; j < 8; ++j) {
    const int n = n0 - j;
    t[j] = (n >= 0 && n < 127) ? tp[n] : 0.0f;
  }
  const f32x4 a = {t[0], t[1], t[2], t[3]};
  const f32x4 b = {t[4], t[5], t[6], t[7]};
  cvt_split8(a, b, fh, fl);
}

// Toeplitz B-operand fragment: value = tp[base + j]  (base in [0,119])
__device__ inline void gen_fragB(const float* tp, int base, bf16x8& fh, bf16x8& fl) {
  float t[8];
  #pragma unroll
  for (int j = 0; j < 8; ++j) t[j] = tp[base + j];
  const f32x4 a = {t[0], t[1], t[2], t[3]};
  const f32x4 b = {t[4], t[5], t[6], t[7]};
  cvt_split8(a, b, fh, fl);
}

__global__ __launch_bounds__(256, 2)
void ssm_mfma_kernel(const float* __restrict__ u,
                     const float* __restrict__ kin,
                     float* __restrict__ y) {
  const int h    = blockIdx.x;
  const int tid  = threadIdx.x;
  const int wid  = tid >> 6;
  const int lane = tid & 63;
  const int ln16 = lane & 15;    // batch col (B/C) / row m (A)
  const int quad = lane >> 4;

  __shared__ alignas(16) char pool[69632];
  auto taps = (float (*)[128]) (pool);
  float* wPad = (float*) (pool + 1536);
  auto stA = (float (*)[68]) (pool + 2048);
  auto stB = (float (*)[68]) (pool + 19456);
  auto scr = (float (*)[68]) (pool + 2048 + wid * 4352);   // own [16][68] slab
  auto sT  = (bf16x8 (*)[2][2][64]) (pool + 36864);
  auto g1T = (bf16x8 (*)[2][2][64]) (pool + 53248);
  auto g2T = (bf16x8 (*)[2][2][64]) (pool + 19456);        // over stB, post-scan

  // --- issue first u loads immediately (HBM latency hides under prologue) ---
  const int cb = 8 * wid;                                   // chunk base
  const float* ub = u + ((size_t)ln16 * kH + h) * kL + 8 * quad;
  float* yb = y + ((size_t)ln16 * kH + h) * kL;
  f32x4 uv[4];
  #pragma unroll
  for (int i = 0; i < 4; ++i)
    uv[i] = *(const f32x4*)(ub + 64 * cb + 32 * (i >> 1) + 4 * (i & 1));

  // ---------------- taps: wave0 shuffle scans (proven) ---------------------
  if (wid == 0) {
    const float kv = kin[h * 64 + lane];
    const float kc = fminf(fmaxf(kv, 0.0625f), 1.0f);
    float ks = kc;
    #pragma unroll
    for (int off = 32; off >= 1; off >>= 1) ks += __shfl_xor(ks, off);
    const float kn = kc / ks;
    const float cc = 1.0f / (1.0f + kn);
    float pp = cc;
    #pragma unroll
    for (int off = 1; off < 64; off <<= 1) {
      const float t = __shfl_up(pp, off);
      if (lane >= off) pp *= t;
    }
    float Pe = __shfl_up(pp, 1);
    if (lane == 0) Pe = 1.0f;
    const float wv = (lane < 63) ? (kn * cc * Pe) : Pe;
    const float gv = kv * Pe;
    float sv = (lane == 0) ? 1.0f : 0.0f;
    for (int rr = 0; rr < 63; ++rr) {
      const float s0 = __shfl(sv, rr);
      const float cf = __shfl(wv, lane - 1 - rr);
      if (lane > rr) sv = fmaf(cf, s0, sv);
    }
    taps[0][lane] = 0.0f;
    taps[1][lane] = 0.0f;
    const float gn = __shfl(gv, lane + 1);
    taps[2][lane] = (lane < 63) ? gn : 0.0f;  // G1: g[(i-j)+64]
    taps[2][64 + lane] = 0.0f;
    taps[0][63 + lane] = sv;                  // S: s[i-j]
    taps[1][63 + lane] = gv;                  // G2: g[i-j]
    if (lane == 0) { taps[0][127] = 0.0f; taps[1][127] = 0.0f; }
    wPad[lane] = wv;
    wPad[64 + lane] = 0.0f;
  }
  __syncthreads();

  // ------- P1: S row-frags (temp), A = S·W (4-term, cols 16*wid) -> stA ----
  //          + sT / g1T table slices for mt = wid
  {
    bf16x8 sH[4][2], sL[4][2];
    #pragma unroll
    for (int mt = 0; mt < 4; ++mt) {
      #pragma unroll
      for (int tk = 0; tk < 2; ++tk) {
        const int n0 = 16 * mt + ln16 - (32 * tk + 8 * quad) + 63;
        gen_frag(taps[0], n0, sH[mt][tk], sL[mt][tk]);
      }
    }
    #pragma unroll
    for (int mt = 0; mt < 4; ++mt) {
      f32x4 acc = {0.f, 0.f, 0.f, 0.f};
      #pragma unroll
      for (int tk = 0; tk < 2; ++tk) {
        const int base = 8 * quad + 32 * tk - (16 * wid + ln16) + 63;
        bf16x8 bh, bl;
        gen_fragB(wPad, base, bh, bl);            // W as B: w[(k-c)+63]
        acc = MFMA(sH[mt][tk], bh, acc);
        acc = MFMA(sH[mt][tk], bl, acc);
        acc = MFMA(sL[mt][tk], bh, acc);
        acc = MFMA(sL[mt][tk], bl, acc);
      }
      #pragma unroll
      for (int r = 0; r < 4; ++r)
        stA[16 * mt + 4 * quad + r][16 * wid + ln16] = acc[r];
    }
    #pragma unroll
    for (int tk = 0; tk < 2; ++tk) {
      const int n0 = 16 * wid + ln16 - (32 * tk + 8 * quad) + 63;
      bf16x8 fh, fl;
      gen_frag(taps[0], n0, fh, fl);
      sT[wid][tk][0][lane] = fh;  sT[wid][tk][1][lane] = fl;
      gen_frag(taps[2], n0, fh, fl);
      g1T[wid][tk][0][lane] = fh; g1T[wid][tk][1][lane] = fl;
    }
  }
  __syncthreads();

  // ------- P2: A row-frags (persistent) ; A^2 = A·A -> stB cols ------------
  bf16x8 aH[4][2], aL[4][2];
  #pragma unroll
  for (int mt = 0; mt < 4; ++mt) {
    #pragma unroll
    for (int tk = 0; tk < 2; ++tk) {
      const int row = 16 * mt + ln16, k0 = 32 * tk + 8 * quad;
      cvt_split8(*(const f32x4*)&stA[row][k0], *(const f32x4*)&stA[row][k0 + 4],
                 aH[mt][tk], aL[mt][tk]);
    }
  }
  #pragma unroll
  for (int mt = 0; mt < 4; ++mt) {
    f32x4 acc = {0.f, 0.f, 0.f, 0.f};
    #pragma unroll
    for (int tk = 0; tk < 2; ++tk) {
      float t[8];
      #pragma unroll
      for (int j = 0; j < 8; ++j)
        t[j] = stA[8 * quad + 32 * tk + j][16 * wid + ln16];   // A cols as B
      const f32x4 a = {t[0], t[1], t[2], t[3]};
      const f32x4 b = {t[4], t[5], t[6], t[7]};
      bf16x8 bh, bl;
      cvt_split8(a, b, bh, bl);
      acc = MFMA(aH[mt][tk], bh, acc);
      acc = MFMA(aH[mt][tk], bl, acc);
      acc = MFMA(aL[mt][tk], bh, acc);
      acc = MFMA(aL[mt][tk], bl, acc);
    }
    #pragma unroll
    for (int r = 0; r < 4; ++r)
      stB[16 * mt + 4 * quad + r][16 * wid + ln16] = acc[r];
  }
  __syncthreads();

  // ------- P3: A^4 = A^2·A^2 (stB -> stA); P4: A^8 = A^4·A^4 (stA -> stB) --
  #pragma unroll
  for (int sq = 0; sq < 2; ++sq) {
    float (*src)[68] = (sq == 0) ? stB : stA;
    float (*dst)[68] = (sq == 0) ? stA : stB;
    #pragma unroll
    for (int mt = 0; mt < 4; ++mt) {
      bf16x8 rh[2], rl[2];
      #pragma unroll
      for (int tk = 0; tk < 2; ++tk) {
        const int row = 16 * mt + ln16, k0 = 32 * tk + 8 * quad;
        cvt_split8(*(const f32x4*)&src[row][k0], *(const f32x4*)&src[row][k0 + 4],
                   rh[tk], rl[tk]);
      }
      f32x4 acc = {0.f, 0.f, 0.f, 0.f};
      #pragma unroll
      for (int tk = 0; tk < 2; ++tk) {
        float t[8];
        #pragma unroll
        for (int j = 0; j < 8; ++j)
          t[j] = src[8 * quad + 32 * tk + j][16 * wid + ln16];
        const f32x4 a = {t[0], t[1], t[2], t[3]};
        const f32x4 b = {t[4], t[5], t[6], t[7]};
        bf16x8 bh, bl;
        cvt_split8(a, b, bh, bl);
        acc = MFMA(rh[tk], bh, acc);
        acc = MFMA(rh[tk], bl, acc);
        acc = MFMA(rl[tk], bh, acc);
        acc = MFMA(rl[tk], bl, acc);
      }
      #pragma unroll
      for (int r = 0; r < 4; ++r)
        dst[16 * mt + 4 * quad + r][16 * wid + ln16] = acc[r];
    }
    __syncthreads();
  }
  // stB = A^8; stA free -> per-wave scratch slabs from here.

  // ---------------- pass 1: zero-init local recurrence (barrier-free) ------
  bf16x8 pH[2], pL[2];
  {
    bf16x8 z;
    #pragma unroll
    for (int j = 0; j < 8; ++j) z[j] = 0;
    pH[0] = z; pH[1] = z; pL[0] = z; pL[1] = z;
  }

  #pragma unroll 1
  for (int i = 0; i < 8; ++i) {
    bf16x8 uH[2], uL[2];
    cvt_split8(uv[0], uv[1], uH[0], uL[0]);
    cvt_split8(uv[2], uv[3], uH[1], uL[1]);
    const int tn = 64 * ((i < 7) ? (cb + i + 1) : cb);       // i=7 preloads pass-2
    #pragma unroll
    for (int q = 0; q < 4; ++q)
      uv[q] = *(const f32x4*)(ub + tn + 32 * (q >> 1) + 4 * (q & 1));

    f32x4 acc[4];
    #pragma unroll
    for (int mt = 0; mt < 4; ++mt) acc[mt] = (f32x4){0.f, 0.f, 0.f, 0.f};
    #pragma unroll
    for (int mt = 0; mt < 4; ++mt) {
      #pragma unroll
      for (int tk = 0; tk < 2; ++tk) {
        acc[mt] = MFMA(aH[mt][tk], pH[tk], acc[mt]);         // A·p (critical)
        acc[mt] = MFMA(aH[mt][tk], pL[tk], acc[mt]);
        acc[mt] = MFMA(aL[mt][tk], pH[tk], acc[mt]);
      }
      #pragma unroll
      for (int tk = 0; tk < 2; ++tk) {
        const bf16x8 th = sT[mt][tk][0][lane];
        const bf16x8 tl = sT[mt][tk][1][lane];
        acc[mt] = MFMA(th, uH[tk], acc[mt]);                 // + S·u
        acc[mt] = MFMA(th, uL[tk], acc[mt]);
        acc[mt] = MFMA(tl, uH[tk], acc[mt]);
      }
    }
    #pragma unroll
    for (int mt = 0; mt < 4; ++mt)
      *(f32x4*)&scr[ln16][16 * mt + 4 * quad] = acc[mt];
    asm volatile("s_waitcnt lgkmcnt(0)" ::: "memory");
    __builtin_amdgcn_sched_barrier(0);
    #pragma unroll
    for (int tk = 0; tk < 2; ++tk) {
      const int k0 = 8 * quad + 32 * tk;
      cvt_split8(*(const f32x4*)&scr[ln16][k0], *(const f32x4*)&scr[ln16][k0 + 4],
                 pH[tk], pL[tk]);                            // new local state
    }
  }
  // scr now holds C_wid (f32). pH/pL hold C_wid frags.

  // ---------------- scan: P_g = sum_{g'<g} (A^8)^{g-g'-1} C_{g'} -----------
  asm volatile("s_waitcnt lgkmcnt(0)" ::: "memory");   // S1: C's visible
  __builtin_amdgcn_s_barrier();
  asm volatile("" ::: "memory");

  bf16x8 c0H[2], c0L[2];
  f32x4 sac1[4], sac2[4];
  {
    float (*s0)[68] = (float (*)[68])(pool + 2048);
    float (*s1)[68] = (float (*)[68])(pool + 2048 + 4352);
    float (*s2)[68] = (float (*)[68])(pool + 2048 + 2 * 4352);
    if (wid == 1) {
      #pragma unroll
      for (int tk = 0; tk < 2; ++tk) {                       // P_1 = C_0
        const int k0 = 8 * quad + 32 * tk;
        cvt_split8(*(const f32x4*)&s0[ln16][k0], *(const f32x4*)&s0[ln16][k0 + 4],
                   pH[tk], pL[tk]);
      }
    } else if (wid == 2) {
      #pragma unroll
      for (int tk = 0; tk < 2; ++tk) {
        const int k0 = 8 * quad + 32 * tk;
        cvt_split8(*(const f32x4*)&s0[ln16][k0], *(const f32x4*)&s0[ln16][k0 + 4],
                   c0H[tk], c0L[tk]);
      }
      #pragma unroll
      for (int mt = 0; mt < 4; ++mt)
        sac1[mt] = *(const f32x4*)&s1[ln16][16 * mt + 4 * quad];      // C_1
    } else if (wid == 3) {
      #pragma unroll
      for (int tk = 0; tk < 2; ++tk) {
        const int k0 = 8 * quad + 32 * tk;
        cvt_split8(*(const f32x4*)&s0[ln16][k0], *(const f32x4*)&s0[ln16][k0 + 4],
                   c0H[tk], c0L[tk]);
      }
      #pragma unroll
      for (int mt = 0; mt < 4; ++mt) {
        sac1[mt] = *(const f32x4*)&s1[ln16][16 * mt + 4 * quad];      // C_1
        sac2[mt] = *(const f32x4*)&s2[ln16][16 * mt + 4 * quad];      // C_2
      }
    }
  }
  asm volatile("s_waitcnt lgkmcnt(0)" ::: "memory");   // S2: reads done
  __builtin_amdgcn_s_barrier();
  asm volatile("" ::: "memory");

  if (wid == 0) {
    bf16x8 z;
    #pragma unroll
    for (int j = 0; j < 8; ++j) z[j] = 0;
    pH[0] = z; pH[1] = z; pL[0] = z; pL[1] = z;              // P_0 = 0
  } else if (wid >= 2) {
    // sac1 += A^8·C_0 (4-term); Horner step 1
    #pragma unroll
    for (int mt = 0; mt < 4; ++mt) {
      bf16x8 a8h[2], a8l[2];
      #pragma unroll
      for (int tk = 0; tk < 2; ++tk) {
        const int row = 16 * mt + ln16, k0 = 32 * tk + 8 * quad;
        cvt_split8(*(const f32x4*)&stB[row][k0], *(const f32x4*)&stB[row][k0 + 4],
                   a8h[tk], a8l[tk]);
      }
      #pragma unroll
      for (int tk = 0; tk < 2; ++tk) {
        sac1[mt] = MFMA(a8h[tk], c0H[tk], sac1[mt]);
        sac1[mt] = MFMA(a8h[tk], c0L[tk], sac1[mt]);
        sac1[mt] = MFMA(a8l[tk], c0H[tk], sac1[mt]);
        sac1[mt] = MFMA(a8l[tk], c0L[tk], sac1[mt]);
      }
    }
    #pragma unroll
    for (int mt = 0; mt < 4; ++mt)
      *(f32x4*)&scr[ln16][16 * mt + 4 * quad] = sac1[mt];
    asm volatile("s_waitcnt lgkmcnt(0)" ::: "memory");
    __builtin_amdgcn_sched_barrier(0);
    #pragma unroll
    for (int tk = 0; tk < 2; ++tk) {
      const int k0 = 8 * quad + 32 * tk;
      cvt_split8(*(const f32x4*)&scr[ln16][k0], *(const f32x4*)&scr[ln16][k0 + 4],
                 pH[tk], pL[tk]);   // wid2: P_2 ; wid3: t = A^8 C_0 + C_1
    }
    if (wid == 3) {
      // P_3 = A^8·t + C_2 (Horner step 2)
      #pragma unroll
      for (int mt = 0; mt < 4; ++mt) {
        bf16x8 a8h[2], a8l[2];
        #pragma unroll
        for (int tk = 0; tk < 2; ++tk) {
          const int row = 16 * mt + ln16, k0 = 32 * tk + 8 * quad;
          cvt_split8(*(const f32x4*)&stB[row][k0], *(const f32x4*)&stB[row][k0 + 4],
                     a8h[tk], a8l[tk]);
        }
        #pragma unroll
        for (int tk = 0; tk < 2; ++tk) {
          sac2[mt] = MFMA(a8h[tk], pH[tk], sac2[mt]);
          sac2[mt] = MFMA(a8h[tk], pL[tk], sac2[mt]);
          sac2[mt] = MFMA(a8l[tk], pH[tk], sac2[mt]);
          sac2[mt] = MFMA(a8l[tk], pL[tk], sac2[mt]);
        }
      }
      #pragma unroll
      for (int mt = 0; mt < 4; ++mt)
        *(f32x4*)&scr[ln16][16 * mt + 4 * quad] = sac2[mt];
      asm volatile("s_waitcnt lgkmcnt(0)" ::: "memory");
      __builtin_amdgcn_sched_barrier(0);
      #pragma unroll
      for (int tk = 0; tk < 2; ++tk) {
        const int k0 = 8 * quad + 32 * tk;
        cvt_split8(*(const f32x4*)&scr[ln16][k0], *(const f32x4*)&scr[ln16][k0 + 4],
                   pH[tk], pL[tk]);                          // P_3
      }
    }
  }
  asm volatile("s_waitcnt lgkmcnt(0)" ::: "memory");   // S3: A^8 reads done
  __builtin_amdgcn_s_barrier();
  asm volatile("" ::: "memory");

  // g2T table slice (over stB region) — built post-scan
  #pragma unroll
  for (int tk = 0; tk < 2; ++tk) {
    const int n0 = 16 * wid + ln16 - (32 * tk + 8 * quad) + 63;
    bf16x8 fh, fl;
    gen_frag(taps[1], n0, fh, fl);
    g2T[wid][tk][0][lane] = fh;  g2T[wid][tk][1][lane] = fl;
  }
  asm volatile("s_waitcnt lgkmcnt(0)" ::: "memory");   // S4: g2T ready
  __builtin_amdgcn_s_barrier();
  asm volatile("" ::: "memory");

  // ---------------- pass 2: replay from true P_g, emit y (barrier-free) ----
  #pragma unroll 1
  for (int i = 0; i < 8; ++i) {
    bf16x8 uH[2], uL[2];
    cvt_split8(uv[0], uv[1], uH[0], uL[0]);
    cvt_split8(uv[2], uv[3], uH[1], uL[1]);
    const int tn = 64 * ((i < 7) ? (cb + i + 1) : cb);
    #pragma unroll
    for (int q = 0; q < 4; ++q)
      uv[q] = *(const f32x4*)(ub + tn + 32 * (q >> 1) + 4 * (q & 1));

    f32x4 accR[4], accY[4];
    #pragma unroll
    for (int mt = 0; mt < 4; ++mt) {
      accR[mt] = (f32x4){0.f, 0.f, 0.f, 0.f};
      accY[mt] = (f32x4){0.f, 0.f, 0.f, 0.f};
    }
    #pragma unroll
    for (int mt = 0; mt < 4; ++mt) {
      #pragma unroll
      for (int tk = 0; tk < 2; ++tk) {
        accR[mt] = MFMA(aH[mt][tk], pH[tk], accR[mt]);       // A·p
        accR[mt] = MFMA(aH[mt][tk], pL[tk], accR[mt]);
        accR[mt] = MFMA(aL[mt][tk], pH[tk], accR[mt]);
      }
      #pragma unroll
      for (int tk = 0; tk < 2; ++tk) {
        const bf16x8 th = sT[mt][tk][0][lane];
        const bf16x8 tl = sT[mt][tk][1][lane];
        accR[mt] = MFMA(th, uH[tk], accR[mt]);               // + S·u
        accR[mt] = MFMA(th, uL[tk], accR[mt]);
        accR[mt] = MFMA(tl, uH[tk], accR[mt]);
      }
    }
    #pragma unroll
    for (int mt = 0; mt < 4; ++mt)
      *(f32x4*)&scr[ln16][16 * mt + 4 * quad] = accR[mt];    // r -> slab
    // y partial with OLD p: G1·p (covers the RT write->read window)
    #pragma unroll
    for (int mt = 0; mt < 4; ++mt) {
      #pragma unroll
      for (int tk = 0; tk < 2; ++tk) {
        const bf16x8 gh = g1T[mt][tk][0][lane];
        const bf16x8 gl = g1T[mt][tk][1][lane];
        accY[mt] = MFMA(gh, pH[tk], accY[mt]);
        accY[mt] = MFMA(gh, pL[tk], accY[mt]);
        accY[mt] = MFMA(gl, pH[tk], accY[mt]);
      }
    }
    asm volatile("s_waitcnt lgkmcnt(0)" ::: "memory");
    __builtin_amdgcn_sched_barrier(0);
    #pragma unroll
    for (int tk = 0; tk < 2; ++tk) {
      const int k0 = 8 * quad + 32 * tk;
      cvt_split8(*(const f32x4*)&scr[ln16][k0], *(const f32x4*)&scr[ln16][k0 + 4],
                 pH[tk], pL[tk]);                            // p <- r
    }
    // y += G2·r ; store
    #pragma unroll
    for (int mt = 0; mt < 4; ++mt) {
      #pragma unroll
      for (int tk = 0; tk < 2; ++tk) {
        const bf16x8 gh = g2T[mt][tk][0][lane];
        const bf16x8 gl = g2T[mt][tk][1][lane];
        accY[mt] = MFMA(gh, pH[tk], accY[mt]);
        accY[mt] = MFMA(gh, pL[tk], accY[mt]);
        accY[mt] = MFMA(gl, pH[tk], accY[mt]);
      }
      *(f32x4*)(yb + 64 * (cb + i) + 16 * mt + 4 * quad) = accY[mt];
    }
  }
}

}  // namespace

extern "C" void kernel_launch(void* const* d_in, const int* in_sizes, int n_in,
                              void* d_out, int out_size, void* d_ws, size_t ws_size,
                              hipStream_t stream) {
  const float* u  = (const float*)d_in[0];   // (16, 512, 2048) fp32
  const float* kk = (const float*)d_in[1];   // (1, 512, 64)    fp32
  if (n_in >= 2 && in_sizes[0] < in_sizes[1]) {
    const float* t = u; u = kk; kk = t;
  }
  float* yy = (float*)d_out;                 // (16, 512, 2048) fp32
  hipLaunchKernelGGL(ssm_mfma_kernel, dim3(kH), dim3(256), 0, stream, u, kk, yy);
}